// Round 1
// 312.331 us; speedup vs baseline: 1.0420x; 1.0420x over previous
//
#include <hip/hip_runtime.h>

#define NE 50000
#define NN 10000
#define KH 96          // real K: 96 (bias injected via MFMA C-init, no padded rows)
#define WN 6928
#define NTILE 484
#define IN_SZ 156
#define EPW 32         // edges per workgroup in tp_kernel

typedef __attribute__((ext_vector_type(8))) short short8;
typedef __attribute__((ext_vector_type(4))) float float4v;

__device__ __forceinline__ unsigned short f2bf(float x) {
  unsigned u = __float_as_uint(x);
  unsigned r = (u + 0x7FFFu + ((u >> 16) & 1u)) >> 16;   // RNE
  return (unsigned short)r;
}
__device__ __forceinline__ float b2f(unsigned short u) {
  return __uint_as_float(((unsigned)u) << 16);
}

// ---- forced-pipeline primitives: volatile asm loads + explicit vmcnt ----
// One B tile = 16 cols x 96 k bf16 = 3072B contiguous in W2PT; lane reads
// base + s*1024 + lane*16 (coalesced 1KB/instr).  4th op loads this tile's
// 16 b2 values (1 dword/lane, 16 lanes broadcast) -> still 4 vmem ops per
// issue, so the vmcnt(4/8) accounting matches the proven r9 idiom.
__device__ __forceinline__ void issue3(short8 (&B)[3], float &bv,
                                       const unsigned short* p, const float* pb) {
  asm volatile("global_load_dwordx4 %0, %4, off\n\t"
               "global_load_dwordx4 %1, %4, off offset:1024\n\t"
               "global_load_dwordx4 %2, %4, off offset:2048\n\t"
               "global_load_dword %3, %5, off"
               : "=&v"(B[0]), "=&v"(B[1]), "=&v"(B[2]), "=&v"(bv)
               : "v"(p), "v"(pb));
}
__device__ __forceinline__ void waitB8(short8 (&B)[3], float &bv) {
  asm volatile("s_waitcnt vmcnt(8)"
               : "+v"(B[0]), "+v"(B[1]), "+v"(B[2]), "+v"(bv));
}
__device__ __forceinline__ void waitB4(short8 (&B)[3], float &bv) {
  asm volatile("s_waitcnt vmcnt(4)"
               : "+v"(B[0]), "+v"(B[1]), "+v"(B[2]), "+v"(bv));
}
__device__ __forceinline__ void waitB0(short8 (&B)[3], float &bv) {
  asm volatile("s_waitcnt vmcnt(0)"
               : "+v"(B[0]), "+v"(B[1]), "+v"(B[2]), "+v"(bv));
}

// permuted column index np -> original W2 column c (or -1 for pad lanes)
__device__ __forceinline__ int col_of_np(int np) {
  if (np < 2784) return np;
  if (np < 3872) { int rel = np - 2784, i = rel >> 4, o = rel & 15; return (o < 10) ? 2784 + i * 10 + o : -1; }
  if (np < 4960) { int rel = np - 3872, i = rel >> 4, o = rel & 15; return (o < 10) ? 3464 + i * 10 + o : -1; }
  return 4144 + (np - 4960);
}

// ---------------- Kernel T: W1 -> bf16 transposed ----------------
__global__ __launch_bounds__(256) void w1t_kernel(
    const float* __restrict__ W1, unsigned short* __restrict__ W1T)
{
  int j = blockIdx.x * 256 + threadIdx.x;
  if (j < KH * KH) {
    int c = j / KH, k = j - c * KH;
    W1T[c * KH + k] = f2bf(W1[k * KH + c]);   // W1T[col][k]
  }
}

// ---------------- Kernel 1: h via MFMA: relu(ea @ W1 + b1); cast fused ----------------
__global__ __launch_bounds__(384) void mlp1_kernel(
    const float* __restrict__ edge_attr, const unsigned short* __restrict__ W1T,
    const float* __restrict__ b1, unsigned short* __restrict__ h_ext)
{
  const int tid = threadIdx.x;
  const int e0 = blockIdx.x * 16;
  const int w = tid >> 6, l = tid & 15, q = (tid >> 4) & 3;

  short8 a[3], b[3];
  #pragma unroll
  for (int s = 0; s < 3; ++s) {
    const float* pa = edge_attr + (size_t)(e0 + l) * KH + s * 32 + q * 8;
    float4 x = *(const float4*)pa, y = *(const float4*)(pa + 4);
    short8 t;
    t[0] = (short)f2bf(x.x); t[1] = (short)f2bf(x.y);
    t[2] = (short)f2bf(x.z); t[3] = (short)f2bf(x.w);
    t[4] = (short)f2bf(y.x); t[5] = (short)f2bf(y.y);
    t[6] = (short)f2bf(y.z); t[7] = (short)f2bf(y.w);
    a[s] = t;
    b[s] = *(const short8*)(W1T + (size_t)(w * 16 + l) * KH + s * 32 + q * 8);
  }
  float4v C = {0.f, 0.f, 0.f, 0.f};
  #pragma unroll
  for (int s = 0; s < 3; ++s)
    C = __builtin_amdgcn_mfma_f32_16x16x32_bf16(a[s], b[s], C, 0, 0, 0);

  float bv = b1[w * 16 + l];
  #pragma unroll
  for (int r = 0; r < 4; ++r)
    h_ext[(size_t)(e0 + q * 4 + r) * KH + w * 16 + l] = f2bf(fmaxf(C[r] + bv, 0.f));
}

// ---------------- Kernel P: tile-major lane-ordered W2PT (K=96) + b2PT ----------------
// W2PT short index = t*1536 + s*512 + lane*8; lane = q*16+l holds
// B[n = t*16+l][k = s*32+q*8 .. +8], k<96.  b2PT[t*16+l] = b2[col] (f32).
__global__ __launch_bounds__(256) void w2pt_kernel(
    const float* __restrict__ W2, const float* __restrict__ b2,
    unsigned short* __restrict__ W2PT, float* __restrict__ b2PT)
{
  int gid = blockIdx.x * 256 + threadIdx.x;
  if (gid < NTILE * 192) {
    int lane = gid & 63, s = (gid >> 6) % 3, t = gid / 192;
    int l = lane & 15, q = lane >> 4;
    int c = col_of_np(t * 16 + l);
    int kbase = s * 32 + q * 8;
    unsigned short o8[8];
    #pragma unroll
    for (int j = 0; j < 8; ++j) {
      int k = kbase + j;
      float v = (c >= 0) ? W2[(size_t)k * WN + c] : 0.f;
      o8[j] = f2bf(v);
    }
    uint4 pk;
    pk.x = o8[0] | ((unsigned)o8[1] << 16);
    pk.y = o8[2] | ((unsigned)o8[3] << 16);
    pk.z = o8[4] | ((unsigned)o8[5] << 16);
    pk.w = o8[6] | ((unsigned)o8[7] << 16);
    *(uint4*)(W2PT + (size_t)gid * 8) = pk;
  } else {
    int j = gid - NTILE * 192;
    if (j < NTILE * 16) {
      int c = col_of_np(j);
      b2PT[j] = (c >= 0) ? b2[c] : 0.f;
    }
  }
}

// ---------------- Kernel 2: MFMA w-GEMM fused with TP ----------------
__global__ __launch_bounds__(512, 4) void tp_kernel(
    const unsigned short* __restrict__ h_ext, const float* __restrict__ node_attr,
    const int* __restrict__ edge_index, const float* __restrict__ edge_sh,
    const unsigned short* __restrict__ W2PT, const float* __restrict__ b2PT,
    float* __restrict__ acc, int* __restrict__ icnt)
{
  __shared__ unsigned short sIn[EPW][160];         // bf16 gathered node_attr
  __shared__ float sOut[EPW][IN_SZ];               // stride 156: 160 was bank-aligned (4-way atomic conflicts)
  __shared__ unsigned short sF0[2][60][EPW];       // scalar feats [fam][i][e]; rows 58,59 = 0
  __shared__ unsigned short sF1[2][68][3][EPW];    // vector feats [fam][i][cc][e]
  __shared__ float sShs[EPW][4];
  __shared__ int sSrc[EPW], sDst[EPW];

  const int tid = threadIdx.x;
  const int e0 = blockIdx.x * EPW;

  if (tid < EPW) {
    int ok = (e0 + tid) < NE;
    int s = ok ? edge_index[e0 + tid] : 0;
    int d = ok ? edge_index[NE + e0 + tid] : 0;
    sSrc[tid] = s; sDst[tid] = d;
    if (ok) atomicAdd(&icnt[s], 1);
  }
  if (tid >= 128 && tid < 256) {
    int t2 = tid - 128;
    int e = t2 >> 2, c = t2 & 3;
    sShs[e][c] = ((e0 + e) < NE) ? edge_sh[(size_t)(e0 + e) * 4 + c] : 0.f;
  }
  __syncthreads();

  for (int idx = tid; idx < EPW * IN_SZ; idx += 512) {
    int e = idx / IN_SZ, f = idx - e * IN_SZ;
    sIn[e][f] = f2bf(node_attr[(size_t)sDst[e] * IN_SZ + f]);
  }
  for (int idx = tid; idx < EPW * IN_SZ; idx += 512) (&sOut[0][0])[idx] = 0.f;
  __syncthreads();

  { // ---- feature construction: 16 workers per edge ----
    const int e = tid >> 4, j = tid & 15;
    const float sh0 = sShs[e][0], sx = sShs[e][1], sy = sShs[e][2], sz = sShs[e][3];
    const float i3 = 0.57735026918962576f, i2 = 0.70710678118654752f;
    for (int i = j; i < 48; i += 16) {
      float v0 = b2f(sIn[e][i]), w0 = b2f(sIn[e][108 + i]);
      sF0[0][i][e] = f2bf(v0 * sh0);
      sF0[1][10 + i][e] = f2bf(w0 * sh0);
      sF1[0][i][0][e] = f2bf(v0 * sx); sF1[0][i][1][e] = f2bf(v0 * sy); sF1[0][i][2][e] = f2bf(v0 * sz);
      sF1[1][20 + i][0][e] = f2bf(w0 * sx); sF1[1][20 + i][1][e] = f2bf(w0 * sy); sF1[1][20 + i][2][e] = f2bf(w0 * sz);
    }
    if (j < 10) {
      const int v = j;
      float ax = b2f(sIn[e][48 + 3 * v]), ay = b2f(sIn[e][48 + 3 * v + 1]), az = b2f(sIn[e][48 + 3 * v + 2]);
      float bx = b2f(sIn[e][78 + 3 * v]), by = b2f(sIn[e][78 + 3 * v + 1]), bz = b2f(sIn[e][78 + 3 * v + 2]);
      sF0[0][48 + v][e] = f2bf((ax * sx + ay * sy + az * sz) * i3);
      sF0[1][v][e]      = f2bf((bx * sx + by * sy + bz * sz) * i3);
      sF1[0][48 + v][0][e] = f2bf(ax * sh0); sF1[0][48 + v][1][e] = f2bf(ay * sh0); sF1[0][48 + v][2][e] = f2bf(az * sh0);
      sF1[0][58 + v][0][e] = f2bf((by * sz - bz * sy) * i2);
      sF1[0][58 + v][1][e] = f2bf((bz * sx - bx * sz) * i2);
      sF1[0][58 + v][2][e] = f2bf((bx * sy - by * sx) * i2);
      sF1[1][v][0][e] = f2bf((ay * sz - az * sy) * i2);
      sF1[1][v][1][e] = f2bf((az * sx - ax * sz) * i2);
      sF1[1][v][2][e] = f2bf((ax * sy - ay * sx) * i2);
      sF1[1][10 + v][0][e] = f2bf(bx * sh0); sF1[1][10 + v][1][e] = f2bf(by * sh0); sF1[1][10 + v][2][e] = f2bf(bz * sh0);
    }
  }
  // zero sF0 pad rows 58,59 (scalar upper-half waves touch them with f=0)
  if (tid < 128) {
    int fam = tid >> 6, i = 58 + ((tid >> 5) & 1), e = tid & 31;
    sF0[fam][i][e] = 0;
  }
  __syncthreads();

  const int wv = tid >> 6, l = tid & 15, q = (tid >> 4) & 3;

  // A fragments for both edge halves (K=96: 3 frags each), live all kernel.
  short8 Af[2][3];
  #pragma unroll
  for (int m = 0; m < 2; ++m) {
    const unsigned short* ar = h_ext + (size_t)(e0 + m * 16 + l) * KH + q * 8;
    #pragma unroll
    for (int s = 0; s < 3; ++s) Af[m][s] = *(const short8*)(ar + s * 32);
  }

  const unsigned short* wlane = W2PT + (size_t)(tid & 63) * 8;  // coalesced: lane*16B
  const float* blane = b2PT + l;                                // b2 for this lane's column

  if (wv < 4) {
    // ---------------- scalar families (0e / 0o): 3-deep pipeline ----------------
    const int sf = wv >> 1;
    const int ibeg = (wv & 1) * 30;
    const int tb = sf ? 310 : 0;
    const int obase = sf ? 108 : 0;
    #pragma unroll 1
    for (int ob = 0; ob < 3; ++ob) {
      float a0[4] = {0.f, 0.f, 0.f, 0.f}, a1[4] = {0.f, 0.f, 0.f, 0.f};
      short8 Ba[3], Bb[3], Bc[3];
      float vA, vB, vC;
      auto taddr = [&](int ii) -> size_t {
        int i = ibeg + ii; if (i >= 58) i = ibeg;       // pad rows -> safe in-family tile
        return (size_t)(tb + 3 * i + ob);
      };
      auto body = [&](const short8 (&B)[3], float bv, int ii) {
        int i = ibeg + ii;
        ushort4 f0 = *(const ushort4*)&sF0[sf][i][q * 4];
        ushort4 f1 = *(const ushort4*)&sF0[sf][i][16 + q * 4];
        float4v C0 = {bv, bv, bv, bv}, C1 = {bv, bv, bv, bv};   // bias via C-init
        #pragma unroll
        for (int s = 0; s < 3; ++s) {
          C0 = __builtin_amdgcn_mfma_f32_16x16x32_bf16(Af[0][s], B[s], C0, 0, 0, 0);
          C1 = __builtin_amdgcn_mfma_f32_16x16x32_bf16(Af[1][s], B[s], C1, 0, 0, 0);
        }
        a0[0] += C0[0] * b2f(f0.x); a0[1] += C0[1] * b2f(f0.y);
        a0[2] += C0[2] * b2f(f0.z); a0[3] += C0[3] * b2f(f0.w);
        a1[0] += C1[0] * b2f(f1.x); a1[1] += C1[1] * b2f(f1.y);
        a1[2] += C1[2] * b2f(f1.z); a1[3] += C1[3] * b2f(f1.w);
      };
      { size_t t = taddr(0); issue3(Ba, vA, wlane + t * 1536, blane + t * 16); }
      { size_t t = taddr(1); issue3(Bb, vB, wlane + t * 1536, blane + t * 16); }
      { size_t t = taddr(2); issue3(Bc, vC, wlane + t * 1536, blane + t * 16); }
      #pragma unroll 1
      for (int ii = 0; ii < 27; ii += 3) {
        waitB8(Ba, vA); body(Ba, vA, ii);
        { size_t t = taddr(ii + 3); issue3(Ba, vA, wlane + t * 1536, blane + t * 16); }
        waitB8(Bb, vB); body(Bb, vB, ii + 1);
        { size_t t = taddr(ii + 4); issue3(Bb, vB, wlane + t * 1536, blane + t * 16); }
        waitB8(Bc, vC); body(Bc, vC, ii + 2);
        { size_t t = taddr(ii + 5); issue3(Bc, vC, wlane + t * 1536, blane + t * 16); }
      }
      waitB8(Ba, vA); body(Ba, vA, 27);
      waitB4(Bb, vB); body(Bb, vB, 28);
      waitB0(Bc, vC); body(Bc, vC, 29);
      const int col = obase + ob * 16 + l;
      #pragma unroll
      for (int r = 0; r < 4; ++r) {
        unsafeAtomicAdd(&sOut[q * 4 + r][col], a0[r]);
        unsafeAtomicAdd(&sOut[16 + q * 4 + r][col], a1[r]);
      }
    }
  } else {
    // ---------------- vector families (1o / 1e): i-halves 34/34, 2-deep ----------------
    const int vf = (wv >> 1) - 2;
    const int ibeg = (wv & 1) * 34;
    const int tb = vf ? 242 : 174;
    float r0[4][3] = {{0.f}}, r1[4][3] = {{0.f}};
    short8 Ba[3], Bb[3];
    float vA, vB;
    auto tadr = [&](int ii) -> size_t { return (size_t)(tb + ibeg + ii); };
    auto body = [&](const short8 (&B)[3], float bv, int ii) {
      int i = ibeg + ii;
      ushort4 g0[3], g1[3];
      #pragma unroll
      for (int cc = 0; cc < 3; ++cc) {
        g0[cc] = *(const ushort4*)&sF1[vf][i][cc][q * 4];
        g1[cc] = *(const ushort4*)&sF1[vf][i][cc][16 + q * 4];
      }
      float4v C0 = {bv, bv, bv, bv}, C1 = {bv, bv, bv, bv};
      #pragma unroll
      for (int s = 0; s < 3; ++s) {
        C0 = __builtin_amdgcn_mfma_f32_16x16x32_bf16(Af[0][s], B[s], C0, 0, 0, 0);
        C1 = __builtin_amdgcn_mfma_f32_16x16x32_bf16(Af[1][s], B[s], C1, 0, 0, 0);
      }
      #pragma unroll
      for (int cc = 0; cc < 3; ++cc) {
        r0[0][cc] += C0[0] * b2f(g0[cc].x); r0[1][cc] += C0[1] * b2f(g0[cc].y);
        r0[2][cc] += C0[2] * b2f(g0[cc].z); r0[3][cc] += C0[3] * b2f(g0[cc].w);
        r1[0][cc] += C1[0] * b2f(g1[cc].x); r1[1][cc] += C1[1] * b2f(g1[cc].y);
        r1[2][cc] += C1[2] * b2f(g1[cc].z); r1[3][cc] += C1[3] * b2f(g1[cc].w);
      }
    };
    { size_t t = tadr(0); issue3(Ba, vA, wlane + t * 1536, blane + t * 16); }
    { size_t t = tadr(1); issue3(Bb, vB, wlane + t * 1536, blane + t * 16); }
    #pragma unroll 1
    for (int ii = 0; ii < 32; ii += 2) {
      waitB4(Ba, vA); body(Ba, vA, ii);
      { size_t t = tadr(ii + 2); issue3(Ba, vA, wlane + t * 1536, blane + t * 16); }
      waitB4(Bb, vB); body(Bb, vB, ii + 1);
      { size_t t = tadr(ii + 3); issue3(Bb, vB, wlane + t * 1536, blane + t * 16); }
    }
    waitB4(Ba, vA); body(Ba, vA, 32);
    waitB0(Bb, vB); body(Bb, vB, 33);
    if (l < 10) {
      const int col = (vf ? 78 : 48) + 3 * l;
      #pragma unroll
      for (int r = 0; r < 4; ++r)
        #pragma unroll
        for (int cc = 0; cc < 3; ++cc) {
          unsafeAtomicAdd(&sOut[q * 4 + r][col + cc], r0[r][cc]);
          unsafeAtomicAdd(&sOut[16 + q * 4 + r][col + cc], r1[r][cc]);
        }
    }
  }
  __syncthreads();

  // ---- scatter to global ----
  const float n58 = 0.13130643285972254f, n68 = 0.12126781251816650f;
  for (int idx = tid; idx < EPW * IN_SZ; idx += 512) {
    int e = idx / IN_SZ, o = idx - e * IN_SZ;
    if (e0 + e < NE) {
      float nrm = (o < 48 || o >= 108) ? n58 : n68;
      unsafeAtomicAdd(&acc[(size_t)sSrc[e] * IN_SZ + o], sOut[e][o] * nrm);
    }
  }
}

// ---------------- Kernel 3: out = acc / max(cnt,1) + node_attr ----------------
__global__ __launch_bounds__(256) void finalize_kernel(
    const float* __restrict__ acc, const int* __restrict__ icnt,
    const float* __restrict__ node_attr, float* __restrict__ out)
{
  int idx = blockIdx.x * 256 + threadIdx.x;
  if (idx < NN * IN_SZ) {
    int n = idx / IN_SZ;
    out[idx] = acc[idx] / fmaxf((float)icnt[n], 1.f) + node_attr[idx];
  }
}

extern "C" void kernel_launch(void* const* d_in, const int* in_sizes, int n_in,
                              void* d_out, int out_size, void* d_ws, size_t ws_size,
                              hipStream_t stream)
{
  const float* node_attr  = (const float*)d_in[0];
  const int*   edge_index = (const int*)d_in[1];
  const float* edge_attr  = (const float*)d_in[2];
  const float* edge_sh    = (const float*)d_in[3];
  const float* W1 = (const float*)d_in[4];
  const float* b1 = (const float*)d_in[5];
  const float* W2 = (const float*)d_in[6];
  const float* b2 = (const float*)d_in[7];
  float* out = (float*)d_out;

  unsigned short* h_ext = (unsigned short*)d_ws;               // 50016 * 96 bf16
  unsigned short* W2PT  = h_ext + (size_t)50016 * KH;          // 484 tiles * 1536 shorts
  float* b2PT = (float*)(W2PT + (size_t)NTILE * 1536);         // 484 * 16 f32
  float* acc  = b2PT + (size_t)NTILE * 16;                     // NN * 156 f32
  int*   icnt = (int*)(acc + (size_t)NN * IN_SZ);              // NN i32
  unsigned short* W1T = (unsigned short*)(icnt + NN);          // 96*96 bf16

  w1t_kernel<<<(KH * KH + 255) / 256, 256, 0, stream>>>(W1, W1T);
  w2pt_kernel<<<(NTILE * 208 + 255) / 256, 256, 0, stream>>>(W2, b2, W2PT, b2PT);
  mlp1_kernel<<<NE / 16, 384, 0, stream>>>(edge_attr, W1T, b1, h_ext);
  hipMemsetAsync(acc, 0, (size_t)NN * IN_SZ * sizeof(float), stream);
  hipMemsetAsync(icnt, 0, (size_t)NN * sizeof(int), stream);
  hipMemsetAsync(h_ext + (size_t)NE * KH, 0, (size_t)16 * KH * sizeof(unsigned short), stream);
  tp_kernel<<<(NE + EPW - 1) / EPW, 512, 0, stream>>>(h_ext, node_attr, edge_index,
                                                      edge_sh, W2PT, b2PT, acc, icnt);
  finalize_kernel<<<(NN * IN_SZ + 255) / 256, 256, 0, stream>>>(acc, icnt, node_attr, out);
}